// Round 9
// baseline (77.461 us; speedup 1.0000x reference)
//
#include <hip/hip_runtime.h>
#include <math.h>

#define HIN 32
#define WIN 32
#define NITER 3

// ---- 8-lane sum entirely on the VALU pipe (DPP), no ds_swizzle ----
template <int CTRL>
__device__ __forceinline__ float dpp_add(float v) {
    int p = __builtin_amdgcn_update_dpp(0, __float_as_int(v), CTRL, 0xF, 0xF, true);
    return v + __int_as_float(p);
}
__device__ __forceinline__ float sum8(float v) {
    v = dpp_add<0xB1>(v);   // quad_perm [1,0,3,2]  = xor 1
    v = dpp_add<0x4E>(v);   // quad_perm [2,3,0,1]  = xor 2
    v = dpp_add<0x141>(v);  // row_half_mirror      = cross-quad in 8-group
    return v;
}

// ---------------- fused routing (single kernel, no prep) ----------------
// Parity path (TH,TW): T = TH*TW taps used; the other 72-8T votes are exactly
// zero -> contribute Z = 72-8T to the softmax denominator (shift-free softmax:
// bounded logits). normalize() is scale-invariant, so iterations carry
// UNNORMALIZED weighted sums r[]; the single rcp(r8+Z) applies at the end.
// Input read directly from (n,c,y,x) (512 KB, L2-resident; 8 scalar loads per
// tap per lane). Weight: stage only the T taps, flipped+swizzled, in-kernel.
// R5 lesson: 1 position/wave, pri <= 32 VGPRs (spill cliff at 2 pos/wave).
template <int TH, int TW>
__device__ __forceinline__ void run_path(
    const float* __restrict__ in, const float* __restrict__ weight,
    const float* __restrict__ bias, float* __restrict__ out,
    float* __restrict__ wlds, float* __restrict__ olds,
    int t, int n, int p, int qb) {
    constexpr int T = TH * TW;
    constexpr float Z = (float)(72 - 8 * T);

    // ---- stage T taps of flipped weight: wlds[(vtap*8+g)*64 + ((m+g)&7)*8 + l]
    {
        const int sg = (t >> 3) & 7;
        const int sm = t & 7;
        const int smg = ((sm + sg) & 7) * 8;
        const int l0 = t >> 6;
#pragma unroll
        for (int k = 0; k < 2 * T; ++k) {
            const int vtap = k >> 1;
            const int chunk = k & 1;
            const int hh = (TH == 1) ? 1 : ((vtap / TW) * 2);
            const int ww = (TW == 1) ? 1 : ((vtap % TW) * 2);
            const int jflip = (2 - hh) * 3 + (2 - ww);  // compile-time
            const int l = chunk * 4 + l0;
            wlds[(vtap * 8 + sg) * 64 + smg + l] =
                weight[(chunk * 256 + t) * 9 + jflip];
        }
    }
    __syncthreads();

    const int wave = t >> 6;
    const int lane = t & 63;
    const int g = lane >> 3;
    const int s = lane & 7;
    const int q = qb + 2 * wave;

    // ---- priors (direct input reads, R1-verified indexing) ----
    const float* inbase = in + (size_t)(n * 64 + s * 8) * (HIN * WIN);
    float pri[T][8];
#pragma unroll
    for (int i = 0; i < TH; ++i) {
        const int h = (TH == 1) ? 1 : i * 2;
        const int y = (p + h - 1) >> 1;
#pragma unroll
        for (int j = 0; j < TW; ++j) {
            const int v = i * TW + j;
            const int w = (TW == 1) ? 1 : j * 2;
            const int x = (q + w - 1) >> 1;
            const bool valid = (y < HIN) && (x < WIN);
            if (valid) {  // block-uniform path, wave-uniform validity
                float xv[8];
#pragma unroll
                for (int l = 0; l < 8; ++l)
                    xv[l] = inbase[(l * HIN + y) * WIN + x];
                const float* wb = wlds + (v * 8 + g) * 64;
#pragma unroll
                for (int m = 0; m < 8; ++m) {
                    const float4* wp = (const float4*)(wb + ((m + g) & 7) * 8);
                    float4 w0 = wp[0], w1 = wp[1];
                    pri[v][m] = xv[0] * w0.x + xv[1] * w0.y + xv[2] * w0.z + xv[3] * w0.w +
                                xv[4] * w1.x + xv[5] * w1.y + xv[6] * w1.z + xv[7] * w1.w;
                }
            } else {
#pragma unroll
                for (int m = 0; m < 8; ++m) pri[v][m] = 0.f;
            }
        }
    }

    // ---- r = unnormalized routing state (init: sum of votes) ----
    float r[9];
#pragma unroll
    for (int m = 0; m < 8; ++m) {
        float a = 0.f;
#pragma unroll
        for (int v = 0; v < T; ++v) a += pri[v][m];
        r[m] = sum8(a);
    }

#pragma unroll
    for (int it = 0; it < NITER; ++it) {
        float sn = 0.f;
#pragma unroll
        for (int m = 0; m < 8; ++m) sn += r[m] * r[m];
        const float inv = __builtin_amdgcn_rsqf(fmaxf(sn, 1e-24f));
        float on[8];
#pragma unroll
        for (int m = 0; m < 8; ++m) on[m] = r[m] * inv;

        float acc[9];  // acc[0..7] numerators, acc[8] = exp-sum
        acc[8] = 0.f;
        float e[T];
#pragma unroll
        for (int v = 0; v < T; ++v) {
            float a = 0.f;
#pragma unroll
            for (int m = 0; m < 8; ++m) a += pri[v][m] * on[m];
            e[v] = __expf(a);
            acc[8] += e[v];
        }
#pragma unroll
        for (int m = 0; m < 8; ++m) {
            float a = 0.f;
#pragma unroll
            for (int v = 0; v < T; ++v) a += e[v] * pri[v][m];
            acc[m] = a;
        }
#pragma unroll
        for (int j = 0; j < 9; ++j) r[j] = sum8(acc[j]);
    }

    // ---- apply deferred softmax denominator, squash, emit ----
    const float invs = __builtin_amdgcn_rcpf(r[8] + Z);  // zero votes: exp(0)=1
    float o[8];
#pragma unroll
    for (int m = 0; m < 8; ++m) o[m] = r[m] * invs;

    float sn = 0.f;
#pragma unroll
    for (int m = 0; m < 8; ++m) sn += o[m] * o[m];
    const float factor =
        sn * __builtin_amdgcn_rcpf(1.f + sn) * __builtin_amdgcn_rsqf(sn + 1e-12f);

    float val = o[0];
#pragma unroll
    for (int m = 1; m < 8; ++m)
        if (s == m) val = o[m];
    val = val * factor + bias[g * 8 + s];

    olds[lane * 5 + wave] = val;

    __syncthreads();
    // store: c2 = t>>2 (channel), w = t&3 -> q = qb + 2w (stride-2, same parity)
    const int c2 = t >> 2, w = t & 3;
    out[(((size_t)n * 64 + c2) * 64 + p) * 64 + qb + 2 * w] = olds[c2 * 5 + w];
}

__global__ __launch_bounds__(256) void caps_routing(
    const float* __restrict__ in, const float* __restrict__ weight,
    const float* __restrict__ bias, float* __restrict__ out) {
    __shared__ float wlds[4 * 512];  // up to 4 staged taps, stride-64 rows
    __shared__ float olds[64 * 5];   // output staging
    const int t = threadIdx.x;

    // parity-grouped positions: all 4 waves of a block share (p&1, q&1)
    // b = n*1024 + p*16 + j ; j: qpar = j>>3, qb = (j&7)*8 + qpar
    const int b = blockIdx.x;
    const int n = b >> 10;
    const int p = (b >> 4) & 63;
    const int j = b & 15;
    const int qpar = j >> 3;
    const int qb = (j & 7) * 8 + qpar;

    if (p & 1) {
        if (qpar)
            run_path<2, 2>(in, weight, bias, out, wlds, olds, t, n, p, qb);
        else
            run_path<2, 1>(in, weight, bias, out, wlds, olds, t, n, p, qb);
    } else {
        if (qpar)
            run_path<1, 2>(in, weight, bias, out, wlds, olds, t, n, p, qb);
        else
            run_path<1, 1>(in, weight, bias, out, wlds, olds, t, n, p, qb);
    }
}

extern "C" void kernel_launch(void* const* d_in, const int* in_sizes, int n_in,
                              void* d_out, int out_size, void* d_ws, size_t ws_size,
                              hipStream_t stream) {
    const float* in = (const float*)d_in[0];
    const float* weight = (const float*)d_in[1];
    const float* bias = (const float*)d_in[2];
    float* out = (float*)d_out;
    (void)d_ws; (void)ws_size;

    caps_routing<<<2048, 256, 0, stream>>>(in, weight, bias, out);
}

// Round 10
// 69.743 us; speedup vs baseline: 1.1107x; 1.1107x over previous
//
#include <hip/hip_runtime.h>
#include <math.h>

#define HIN 32
#define WIN 32
#define NITER 3
#define TIN_ELEMS 131072  // 2*32*32*64

typedef float f2 __attribute__((ext_vector_type(2)));
__device__ __forceinline__ f2 mk2(float a, float b) { f2 r; r.x = a; r.y = b; return r; }
__device__ __forceinline__ f2 fma2(f2 a, f2 b, f2 c) { return __builtin_elementwise_fma(a, b, c); }

// ---------------- prep: input transpose + weight permute ----------------
// blocks 0..63: (n,c,y,x) -> (n,y,x,c)
// block 64: weight -> wprep, per tap block of 640 floats:
//   wprep[tap*640 + g*80 + ((m2+g)&3)*20 + l*2 + h] = weight[l][g][2*m2+h][2-kh][2-kw]
//   (m2-pair rows, rotated by g, stride-20 rows / stride-80 g: the routing
//    b128 reads land 2 addresses per bank quad = 2-way = free)
__global__ __launch_bounds__(256) void prep(const float* __restrict__ in,
                                            const float* __restrict__ weight,
                                            float* __restrict__ tin,
                                            float* __restrict__ wprep) {
    __shared__ float lds[64 * 33];
    const int b = blockIdx.x;
    const int t = threadIdx.x;
    if (b < 64) {
        const int n = b >> 5;
        const int s0 = (b & 31) << 5;
        const float* ib = in + n * 65536;
        float* ob = tin + n * 65536;
#pragma unroll
        for (int k = 0; k < 8; ++k) {
            int idx = k * 256 + t;
            int c = idx >> 5, sl = idx & 31;
            lds[c * 33 + sl] = ib[c * 1024 + s0 + sl];
        }
        __syncthreads();
#pragma unroll
        for (int k = 0; k < 8; ++k) {
            int idx = k * 256 + t;
            int sl = idx >> 6, c = idx & 63;
            ob[(size_t)(s0 + sl) * 64 + c] = lds[c * 33 + sl];
        }
    } else {
#pragma unroll
        for (int k = 0; k < 2; ++k) {
            const int lgm = k * 256 + t;
            const int l = lgm >> 6, g = (lgm >> 3) & 7, m = lgm & 7;
            const int m2 = m >> 1, h = m & 1;
            const float* src = weight + lgm * 9;  // [l][g][m][kh][kw]
            float* base = wprep + g * 80 + ((m2 + g) & 3) * 20 + l * 2 + h;
#pragma unroll
            for (int kh = 0; kh < 3; ++kh)
#pragma unroll
                for (int kw = 0; kw < 3; ++kw) {
                    const int tap = (2 - kh) * 3 + (2 - kw);  // flip
                    base[tap * 640] = src[kh * 3 + kw];
                }
        }
    }
}

// ---- 8-lane sum entirely on the VALU pipe (DPP), no ds_swizzle ----
template <int CTRL>
__device__ __forceinline__ float dpp_add(float v) {
    int p = __builtin_amdgcn_update_dpp(0, __float_as_int(v), CTRL, 0xF, 0xF, true);
    return v + __int_as_float(p);
}
__device__ __forceinline__ float sum8(float v) {
    v = dpp_add<0xB1>(v);   // quad_perm xor1
    v = dpp_add<0x4E>(v);   // quad_perm xor2
    v = dpp_add<0x141>(v);  // row_half_mirror
    return v;
}

// ---------------- routing ----------------
// R7 skeleton (best: tin + LDS-staged weights) with the m-dimension packed as
// float2 pairs -> v_pk_fma_f32 halves the FMA issue count (priors, dots,
// weighted sums). T = TH*TW taps; other 72-8T votes are exactly zero ->
// contribute Z to the deferred softmax denominator (shift-free, bounded
// logits). R5 lesson: 1 position/wave, pri <= 32 VGPRs.
template <int TH, int TW>
__device__ __forceinline__ void run_path(
    const float* __restrict__ tin, const float* __restrict__ wprep,
    const float* __restrict__ bias, float* __restrict__ out,
    float* __restrict__ wlds, float* __restrict__ olds,
    int t, int n, int p, int qb) {
    constexpr int T = TH * TW;
    constexpr float Z = (float)(72 - 8 * T);

    const int wave = t >> 6;
    const int lane = t & 63;

    // ---- stage T taps (contiguous 640-float copy per tap, full-BW) ----
    if (wave < T) {
        const int hh = (TH == 1) ? 1 : ((TW == 2 ? (wave >> 1) : wave) * 2);
        const int ww = (TW == 1) ? 1 : ((wave & 1) * 2);
        const float4* src = (const float4*)(wprep + (hh * 3 + ww) * 640);
        float4* dst = (float4*)(wlds + wave * 640);
#pragma unroll
        for (int k = 0; k < 3; ++k) {
            const int idx = k * 64 + lane;
            if (k < 2 || lane < 32) dst[idx] = src[idx];  // 160 float4 = 640 floats
        }
    }
    __syncthreads();

    const int g = lane >> 3;
    const int s = lane & 7;
    const int q = qb + 2 * wave;

    // ---- priors: pri2[v][m2] = (pri[v][2m2], pri[v][2m2+1]) ----
    f2 pri2[T][4];
#pragma unroll
    for (int i = 0; i < TH; ++i) {
        const int h = (TH == 1) ? 1 : i * 2;
        const int y = (p + h - 1) >> 1;
#pragma unroll
        for (int j = 0; j < TW; ++j) {
            const int v = i * TW + j;
            const int w = (TW == 1) ? 1 : j * 2;
            const int x = (q + w - 1) >> 1;
            const bool valid = (y < HIN) && (x < WIN);
            if (valid) {  // block-uniform path, wave-uniform validity
                const float4* xp =
                    (const float4*)(tin + (((size_t)n * HIN + y) * WIN + x) * 64 + s * 8);
                float4 x0 = xp[0], x1 = xp[1];
                float xv[8] = {x0.x, x0.y, x0.z, x0.w, x1.x, x1.y, x1.z, x1.w};
                const float* wb = wlds + v * 640 + g * 80;
#pragma unroll
                for (int m2 = 0; m2 < 4; ++m2) {
                    const float4* row = (const float4*)(wb + ((m2 + g) & 3) * 20);
                    f2 acc = mk2(0.f, 0.f);
#pragma unroll
                    for (int k = 0; k < 4; ++k) {
                        float4 w4 = row[k];  // l=2k:(m,m+1), l=2k+1:(m,m+1)
                        acc = fma2(mk2(xv[2 * k], xv[2 * k]), mk2(w4.x, w4.y), acc);
                        acc = fma2(mk2(xv[2 * k + 1], xv[2 * k + 1]), mk2(w4.z, w4.w), acc);
                    }
                    pri2[v][m2] = acc;
                }
            } else {
#pragma unroll
                for (int m2 = 0; m2 < 4; ++m2) pri2[v][m2] = mk2(0.f, 0.f);
            }
        }
    }

    // ---- init: unnormalized sum of votes, reduced over the 8 s-lanes ----
    f2 rr[4];
#pragma unroll
    for (int m2 = 0; m2 < 4; ++m2) {
        f2 a = mk2(0.f, 0.f);
#pragma unroll
        for (int v = 0; v < T; ++v) a += pri2[v][m2];
        rr[m2].x = sum8(a.x);
        rr[m2].y = sum8(a.y);
    }

    float r8v = 0.f;
#pragma unroll
    for (int it = 0; it < NITER; ++it) {
        f2 t2 = mk2(0.f, 0.f);
#pragma unroll
        for (int m2 = 0; m2 < 4; ++m2) t2 = fma2(rr[m2], rr[m2], t2);
        const float sn = t2.x + t2.y;
        const float inv = __builtin_amdgcn_rsqf(fmaxf(sn, 1e-24f));
        const f2 inv2 = mk2(inv, inv);
        f2 on2[4];
#pragma unroll
        for (int m2 = 0; m2 < 4; ++m2) on2[m2] = rr[m2] * inv2;

        float a8 = 0.f;
        f2 acc2[4];
#pragma unroll
        for (int m2 = 0; m2 < 4; ++m2) acc2[m2] = mk2(0.f, 0.f);
#pragma unroll
        for (int v = 0; v < T; ++v) {
            f2 d2 = mk2(0.f, 0.f);
#pragma unroll
            for (int m2 = 0; m2 < 4; ++m2) d2 = fma2(pri2[v][m2], on2[m2], d2);
            const float e = __expf(d2.x + d2.y);
            a8 += e;
            const f2 e2 = mk2(e, e);
#pragma unroll
            for (int m2 = 0; m2 < 4; ++m2) acc2[m2] = fma2(e2, pri2[v][m2], acc2[m2]);
        }
#pragma unroll
        for (int m2 = 0; m2 < 4; ++m2) {
            rr[m2].x = sum8(acc2[m2].x);
            rr[m2].y = sum8(acc2[m2].y);
        }
        if (it == NITER - 1) r8v = sum8(a8);  // denominator only needed once
    }

    // ---- deferred softmax denominator + squash + emit ----
    const float invs = __builtin_amdgcn_rcpf(r8v + Z);  // zero votes: exp(0)=1
    const f2 invs2 = mk2(invs, invs);
    f2 o2[4];
#pragma unroll
    for (int m2 = 0; m2 < 4; ++m2) o2[m2] = rr[m2] * invs2;

    f2 s2 = mk2(0.f, 0.f);
#pragma unroll
    for (int m2 = 0; m2 < 4; ++m2) s2 = fma2(o2[m2], o2[m2], s2);
    const float sn = s2.x + s2.y;
    const float factor =
        sn * __builtin_amdgcn_rcpf(1.f + sn) * __builtin_amdgcn_rsqf(sn + 1e-12f);

    // lane s emits dim m = s: pair index s>>1, component s&1
    f2 osel = o2[0];
#pragma unroll
    for (int m2 = 1; m2 < 4; ++m2)
        if ((s >> 1) == m2) osel = o2[m2];
    float val = (s & 1) ? osel.y : osel.x;
    val = val * factor + bias[g * 8 + s];

    olds[lane * 5 + wave] = val;

    __syncthreads();
    // store: c2 = t>>2 (channel), w = t&3 -> q = qb + 2w (stride-2, same parity)
    const int c2 = t >> 2, w = t & 3;
    out[(((size_t)n * 64 + c2) * 64 + p) * 64 + qb + 2 * w] = olds[c2 * 5 + w];
}

__global__ __launch_bounds__(256) void caps_routing(
    const float* __restrict__ tin, const float* __restrict__ wprep,
    const float* __restrict__ bias, float* __restrict__ out) {
    __shared__ float wlds[4 * 640];  // up to 4 staged taps (640 floats each)
    __shared__ float olds[64 * 5];   // output staging
    const int t = threadIdx.x;

    // parity-grouped positions: all 4 waves of a block share (p&1, q&1)
    const int b = blockIdx.x;
    const int n = b >> 10;
    const int p = (b >> 4) & 63;
    const int j = b & 15;
    const int qpar = j >> 3;
    const int qb = (j & 7) * 8 + qpar;

    if (p & 1) {
        if (qpar)
            run_path<2, 2>(tin, wprep, bias, out, wlds, olds, t, n, p, qb);
        else
            run_path<2, 1>(tin, wprep, bias, out, wlds, olds, t, n, p, qb);
    } else {
        if (qpar)
            run_path<1, 2>(tin, wprep, bias, out, wlds, olds, t, n, p, qb);
        else
            run_path<1, 1>(tin, wprep, bias, out, wlds, olds, t, n, p, qb);
    }
}

extern "C" void kernel_launch(void* const* d_in, const int* in_sizes, int n_in,
                              void* d_out, int out_size, void* d_ws, size_t ws_size,
                              hipStream_t stream) {
    const float* in = (const float*)d_in[0];
    const float* weight = (const float*)d_in[1];
    const float* bias = (const float*)d_in[2];
    float* out = (float*)d_out;
    float* tin = (float*)d_ws;
    float* wprep = (float*)d_ws + TIN_ELEMS;

    prep<<<65, 256, 0, stream>>>(in, weight, tin, wprep);
    caps_routing<<<2048, 256, 0, stream>>>(tin, wprep, bias, out);
}

// Round 11
// 68.373 us; speedup vs baseline: 1.1329x; 1.0200x over previous
//
#include <hip/hip_runtime.h>
#include <math.h>

#define HIN 32
#define WIN 32
#define NITER 3

typedef float f2 __attribute__((ext_vector_type(2)));
__device__ __forceinline__ f2 mk2(float a, float b) { f2 r; r.x = a; r.y = b; return r; }
__device__ __forceinline__ f2 fma2(f2 a, f2 b, f2 c) { return __builtin_elementwise_fma(a, b, c); }

// ---- 8-lane sum entirely on the VALU pipe (DPP), no ds_swizzle ----
template <int CTRL>
__device__ __forceinline__ float dpp_add(float v) {
    int p = __builtin_amdgcn_update_dpp(0, __float_as_int(v), CTRL, 0xF, 0xF, true);
    return v + __int_as_float(p);
}
__device__ __forceinline__ float sum8(float v) {
    v = dpp_add<0xB1>(v);   // quad_perm xor1
    v = dpp_add<0x4E>(v);   // quad_perm xor2
    v = dpp_add<0x141>(v);  // row_half_mirror
    return v;
}

// ---------------- fused routing (single kernel, block-staged input) ----------
// Parity-grouped block: 4 waves share (p&1,q&1); q = qb + 2*wave. The block's
// input footprint is 64ch x <=2 rows x 8 x-values, with x-window base
// x0 = (b&7)*4 ALWAYS 16B-aligned -> staged once into LDS via one guarded
// float4 load/thread (R9 lesson: never re-read strided scalars per tap).
// ilds layout [y][x][c]: tap reads are the same free 2-way-banked
// ds_read_b128 pattern as the old tin path. Weight: T taps staged from global
// (R8: measured ~free) into the R10 pk layout
//   wlds[vtap*640 + g*80 + ((m2+g)&3)*20 + l*2 + h]  (v_pk_fma_f32 pairs).
// Routing math: m-dim packed f2; unnormalized r[] carried across iterations
// (normalize is scale-invariant); zero votes add Z = 72-8T to the deferred
// softmax denominator (shift-free: bounded logits). R5: 1 pos/wave, no spill.
template <int TH, int TW>
__device__ __forceinline__ void run_path(
    const float* __restrict__ weight, const float* __restrict__ bias,
    float* __restrict__ out, const float* __restrict__ ilds,
    float* __restrict__ wlds, float* __restrict__ olds,
    int t, int n, int p, int qb, int x0) {
    constexpr int T = TH * TW;
    constexpr float Z = (float)(72 - 8 * T);

    // ---- stage T taps of weight (flipped), pk layout ----
    {
        const int sg = (t >> 3) & 7;
        const int sm = t & 7;
        const int l0 = t >> 6;
        const int dbase = sg * 80 + (((sm >> 1) + sg) & 3) * 20 + (sm & 1);
#pragma unroll
        for (int k = 0; k < 2 * T; ++k) {
            const int vtap = k >> 1;
            const int chunk = k & 1;
            const int hh = (TH == 1) ? 1 : ((vtap / TW) * 2);
            const int ww = (TW == 1) ? 1 : ((vtap % TW) * 2);
            const int jflip = (2 - hh) * 3 + (2 - ww);  // compile-time
            const int l = chunk * 4 + l0;
            wlds[vtap * 640 + dbase + l * 2] =
                weight[(chunk * 256 + t) * 9 + jflip];
        }
    }
    __syncthreads();

    const int wave = t >> 6;
    const int lane = t & 63;
    const int g = lane >> 3;
    const int s = lane & 7;
    const int q = qb + 2 * wave;

    // ---- priors from the LDS input tile ----
    f2 pri2[T][4];
#pragma unroll
    for (int i = 0; i < TH; ++i) {
        const int h = (TH == 1) ? 1 : i * 2;
        const int y = (p + h - 1) >> 1;
#pragma unroll
        for (int j = 0; j < TW; ++j) {
            const int v = i * TW + j;
            const int w = (TW == 1) ? 1 : j * 2;
            const int x = (q + w - 1) >> 1;
            const bool valid = (y < HIN) && (x < WIN);
            if (valid) {  // block-uniform path, wave-uniform validity
                const float4* xp =
                    (const float4*)(ilds + ((i * 8) + (x - x0)) * 64 + s * 8);
                float4 x0v = xp[0], x1v = xp[1];
                float xv[8] = {x0v.x, x0v.y, x0v.z, x0v.w, x1v.x, x1v.y, x1v.z, x1v.w};
                const float* wb = wlds + v * 640 + g * 80;
#pragma unroll
                for (int m2 = 0; m2 < 4; ++m2) {
                    const float4* row = (const float4*)(wb + ((m2 + g) & 3) * 20);
                    f2 acc = mk2(0.f, 0.f);
#pragma unroll
                    for (int k = 0; k < 4; ++k) {
                        float4 w4 = row[k];  // l=2k:(m,m+1), l=2k+1:(m,m+1)
                        acc = fma2(mk2(xv[2 * k], xv[2 * k]), mk2(w4.x, w4.y), acc);
                        acc = fma2(mk2(xv[2 * k + 1], xv[2 * k + 1]), mk2(w4.z, w4.w), acc);
                    }
                    pri2[v][m2] = acc;
                }
            } else {
#pragma unroll
                for (int m2 = 0; m2 < 4; ++m2) pri2[v][m2] = mk2(0.f, 0.f);
            }
        }
    }

    // ---- init: unnormalized vote sum, reduced over the 8 s-lanes ----
    f2 rr[4];
#pragma unroll
    for (int m2 = 0; m2 < 4; ++m2) {
        f2 a = mk2(0.f, 0.f);
#pragma unroll
        for (int v = 0; v < T; ++v) a += pri2[v][m2];
        rr[m2].x = sum8(a.x);
        rr[m2].y = sum8(a.y);
    }

    float r8v = 0.f;
#pragma unroll
    for (int it = 0; it < NITER; ++it) {
        f2 t2 = mk2(0.f, 0.f);
#pragma unroll
        for (int m2 = 0; m2 < 4; ++m2) t2 = fma2(rr[m2], rr[m2], t2);
        const float sn = t2.x + t2.y;
        const float inv = __builtin_amdgcn_rsqf(fmaxf(sn, 1e-24f));
        const f2 inv2 = mk2(inv, inv);
        f2 on2[4];
#pragma unroll
        for (int m2 = 0; m2 < 4; ++m2) on2[m2] = rr[m2] * inv2;

        float a8 = 0.f;
        f2 acc2[4];
#pragma unroll
        for (int m2 = 0; m2 < 4; ++m2) acc2[m2] = mk2(0.f, 0.f);
#pragma unroll
        for (int v = 0; v < T; ++v) {
            f2 d2 = mk2(0.f, 0.f);
#pragma unroll
            for (int m2 = 0; m2 < 4; ++m2) d2 = fma2(pri2[v][m2], on2[m2], d2);
            const float e = __expf(d2.x + d2.y);
            a8 += e;
            const f2 e2 = mk2(e, e);
#pragma unroll
            for (int m2 = 0; m2 < 4; ++m2) acc2[m2] = fma2(e2, pri2[v][m2], acc2[m2]);
        }
#pragma unroll
        for (int m2 = 0; m2 < 4; ++m2) {
            rr[m2].x = sum8(acc2[m2].x);
            rr[m2].y = sum8(acc2[m2].y);
        }
        if (it == NITER - 1) r8v = sum8(a8);  // denominator only needed once
    }

    // ---- deferred softmax denominator + squash + emit ----
    const float invs = __builtin_amdgcn_rcpf(r8v + Z);  // zero votes: exp(0)=1
    const f2 invs2 = mk2(invs, invs);
    f2 o2[4];
#pragma unroll
    for (int m2 = 0; m2 < 4; ++m2) o2[m2] = rr[m2] * invs2;

    f2 s2 = mk2(0.f, 0.f);
#pragma unroll
    for (int m2 = 0; m2 < 4; ++m2) s2 = fma2(o2[m2], o2[m2], s2);
    const float sn = s2.x + s2.y;
    const float factor =
        sn * __builtin_amdgcn_rcpf(1.f + sn) * __builtin_amdgcn_rsqf(sn + 1e-12f);

    f2 osel = o2[0];
#pragma unroll
    for (int m2 = 1; m2 < 4; ++m2)
        if ((s >> 1) == m2) osel = o2[m2];
    float val = (s & 1) ? osel.y : osel.x;
    val = val * factor + bias[g * 8 + s];

    olds[lane * 5 + wave] = val;

    __syncthreads();
    // store: c2 = t>>2 (channel), w = t&3 -> q = qb + 2w (stride-2, same parity)
    const int c2 = t >> 2, w = t & 3;
    out[(((size_t)n * 64 + c2) * 64 + p) * 64 + qb + 2 * w] = olds[c2 * 5 + w];
}

__global__ __launch_bounds__(256) void caps_routing(
    const float* __restrict__ in, const float* __restrict__ weight,
    const float* __restrict__ bias, float* __restrict__ out) {
    __shared__ float ilds[2 * 8 * 64];  // input tile [y][x][c]
    __shared__ float wlds[4 * 640];     // up to 4 staged taps (pk layout)
    __shared__ float olds[64 * 5];      // output staging
    const int t = threadIdx.x;

    // b = n*1024 + p*16 + j ; j: qpar = j>>3, qb = (j&7)*8 + qpar
    const int b = blockIdx.x;
    const int n = b >> 10;
    const int p = (b >> 4) & 63;
    const int j = b & 15;
    const int qpar = j >> 3;
    const int qb = (j & 7) * 8 + qpar;
    const int x0 = (j & 7) * 4;   // x-window base, 16B-aligned by construction
    const int y0 = p >> 1;        // first input row; p odd also uses y0+1
    const int nrows = (p & 1) ? 2 : 1;

    // ---- stage input tile: one guarded float4 load per thread ----
    {
        const int c = t >> 2, r = t & 3;
        const int yi = r >> 1, f4 = r & 1;
        const int chunk = x0 + f4 * 4;
        const int y = y0 + yi;
        float4 vv = {0.f, 0.f, 0.f, 0.f};
        if (yi < nrows && y < HIN && chunk < WIN)
            vv = *(const float4*)(in + (((size_t)(n * 64 + c) * HIN + y) * WIN + chunk));
        ilds[(yi * 8 + f4 * 4 + 0) * 64 + c] = vv.x;
        ilds[(yi * 8 + f4 * 4 + 1) * 64 + c] = vv.y;
        ilds[(yi * 8 + f4 * 4 + 2) * 64 + c] = vv.z;
        ilds[(yi * 8 + f4 * 4 + 3) * 64 + c] = vv.w;
    }
    // (no barrier here: run_path's post-weight-staging __syncthreads covers both)

    if (p & 1) {
        if (qpar)
            run_path<2, 2>(weight, bias, out, ilds, wlds, olds, t, n, p, qb, x0);
        else
            run_path<2, 1>(weight, bias, out, ilds, wlds, olds, t, n, p, qb, x0);
    } else {
        if (qpar)
            run_path<1, 2>(weight, bias, out, ilds, wlds, olds, t, n, p, qb, x0);
        else
            run_path<1, 1>(weight, bias, out, ilds, wlds, olds, t, n, p, qb, x0);
    }
}

extern "C" void kernel_launch(void* const* d_in, const int* in_sizes, int n_in,
                              void* d_out, int out_size, void* d_ws, size_t ws_size,
                              hipStream_t stream) {
    const float* in = (const float*)d_in[0];
    const float* weight = (const float*)d_in[1];
    const float* bias = (const float*)d_in[2];
    float* out = (float*)d_out;
    (void)d_ws; (void)ws_size;

    caps_routing<<<2048, 256, 0, stream>>>(in, weight, bias, out);
}

// Round 12
// 66.190 us; speedup vs baseline: 1.1703x; 1.0330x over previous
//
#include <hip/hip_runtime.h>
#include <math.h>

#define HIN 32
#define WIN 32
#define NITER 3

typedef float f2 __attribute__((ext_vector_type(2)));
static __device__ __forceinline__ f2 mk2(float a, float b) { f2 r; r.x = a; r.y = b; return r; }
static __device__ __forceinline__ f2 fma2(f2 a, f2 b, f2 c) { return __builtin_elementwise_fma(a, b, c); }

// ---- 8-lane sum entirely on the VALU pipe (DPP), no ds_swizzle ----
template <int CTRL>
__device__ __forceinline__ float dpp_add(float v) {
    int p = __builtin_amdgcn_update_dpp(0, __float_as_int(v), CTRL, 0xF, 0xF, true);
    return v + __int_as_float(p);
}
__device__ __forceinline__ float sum8(float v) {
    v = dpp_add<0xB1>(v);   // quad_perm xor1
    v = dpp_add<0x4E>(v);   // quad_perm xor2
    v = dpp_add<0x141>(v);  // row_half_mirror
    return v;
}

// ---- stage T taps of flipped weight into pk layout ----
//   wlds[vtap*640 + g*80 + ((m2+g)&3)*20 + l*2 + h]   (v_pk_fma_f32 pairs)
template <int TH, int TW>
__device__ __forceinline__ void stage_weights(const float* __restrict__ weight,
                                              float* __restrict__ wlds, int t) {
    constexpr int T = TH * TW;
    const int sg = (t >> 3) & 7;
    const int sm = t & 7;
    const int l0 = t >> 6;
    const int dbase = sg * 80 + (((sm >> 1) + sg) & 3) * 20 + (sm & 1);
#pragma unroll
    for (int k = 0; k < 2 * T; ++k) {
        const int vtap = k >> 1;
        const int chunk = k & 1;
        const int hh = (TH == 1) ? 1 : ((vtap / TW) * 2);
        const int ww = (TW == 1) ? 1 : ((vtap % TW) * 2);
        const int jflip = (2 - hh) * 3 + (2 - ww);  // compile-time flip
        const int l = chunk * 4 + l0;
        wlds[vtap * 640 + dbase + l * 2] = weight[(chunk * 256 + t) * 9 + jflip];
    }
}

// ---- stage the block's input tile [yi][xi<12][c] (zero-filled OOB) ----
template <int NROWS, int NCHUNK>
__device__ __forceinline__ void stage_input(const float* __restrict__ in,
                                            float* __restrict__ ilds,
                                            int t, int n, int y0, int x0) {
    const int c = t >> 2, r = t & 3;
#pragma unroll
    for (int pp = r; pp < NROWS * NCHUNK; pp += 4) {  // <=4 pairs: 1 iter/thread
        const int yi = pp / NCHUNK, ch = pp % NCHUNK; // compile-time folds
        const int y = y0 + yi;
        const int xc = x0 + ch * 4;
        float4 vv = {0.f, 0.f, 0.f, 0.f};
        if (y < HIN && xc < WIN)
            vv = *(const float4*)(in + (((size_t)(n * 64 + c) * HIN + y) * WIN + xc));
        ilds[(yi * 12 + ch * 4 + 0) * 64 + c] = vv.x;
        ilds[(yi * 12 + ch * 4 + 1) * 64 + c] = vv.y;
        ilds[(yi * 12 + ch * 4 + 2) * 64 + c] = vv.z;
        ilds[(yi * 12 + ch * 4 + 3) * 64 + c] = vv.w;
    }
}

// ---- priors for one position q (m-dim packed f2; invalid taps -> zero votes)
template <int TH, int TW>
__device__ __forceinline__ void compute_pri(const float* __restrict__ ilds,
                                            const float* __restrict__ wlds,
                                            int q, int x0, int pi, int g, int s,
                                            f2 (&pri2)[TH * TW][4]) {
#pragma unroll
    for (int i = 0; i < TH; ++i) {
        const int y = (TH == 1) ? pi : (pi + i);
        const bool vy = (y < HIN);
#pragma unroll
        for (int j = 0; j < TW; ++j) {
            const int v = i * TW + j;
            const int w = (TW == 1) ? 1 : j * 2;
            const int x = (q + w - 1) >> 1;
            if (vy && x < WIN) {  // wave-uniform
                const float4* xp =
                    (const float4*)(ilds + (i * 12 + (x - x0)) * 64 + s * 8);
                float4 x0v = xp[0], x1v = xp[1];
                float xv[8] = {x0v.x, x0v.y, x0v.z, x0v.w, x1v.x, x1v.y, x1v.z, x1v.w};
                const float* wb = wlds + v * 640 + g * 80;
#pragma unroll
                for (int m2 = 0; m2 < 4; ++m2) {
                    const float4* row = (const float4*)(wb + ((m2 + g) & 3) * 20);
                    f2 acc = mk2(0.f, 0.f);
#pragma unroll
                    for (int k = 0; k < 4; ++k) {
                        float4 w4 = row[k];
                        acc = fma2(mk2(xv[2 * k], xv[2 * k]), mk2(w4.x, w4.y), acc);
                        acc = fma2(mk2(xv[2 * k + 1], xv[2 * k + 1]), mk2(w4.z, w4.w), acc);
                    }
                    pri2[v][m2] = acc;
                }
            } else {
#pragma unroll
                for (int m2 = 0; m2 < 4; ++m2) pri2[v][m2] = mk2(0.f, 0.f);
            }
        }
    }
}

// ---- full routing for one position: unnormalized r[] carried across iters
// (normalize is scale-invariant); zero votes add Z = 72-8T to the deferred
// softmax denominator (shift-free: bounded logits). Returns val (+bias).
template <int T>
__device__ __forceinline__ float route_core(const f2 (&pri2)[T][4],
                                            const float* __restrict__ bias,
                                            int g, int s) {
    constexpr float Z = (float)(72 - 8 * T);
    f2 rr[4];
#pragma unroll
    for (int m2 = 0; m2 < 4; ++m2) {
        f2 a = mk2(0.f, 0.f);
#pragma unroll
        for (int v = 0; v < T; ++v) a += pri2[v][m2];
        rr[m2].x = sum8(a.x);
        rr[m2].y = sum8(a.y);
    }
    float r8v = 0.f;
#pragma unroll
    for (int it = 0; it < NITER; ++it) {
        f2 t2 = mk2(0.f, 0.f);
#pragma unroll
        for (int m2 = 0; m2 < 4; ++m2) t2 = fma2(rr[m2], rr[m2], t2);
        const float sn = t2.x + t2.y;
        const float inv = __builtin_amdgcn_rsqf(fmaxf(sn, 1e-24f));
        const f2 inv2 = mk2(inv, inv);
        f2 on2[4];
#pragma unroll
        for (int m2 = 0; m2 < 4; ++m2) on2[m2] = rr[m2] * inv2;

        float a8 = 0.f;
        f2 acc2[4];
#pragma unroll
        for (int m2 = 0; m2 < 4; ++m2) acc2[m2] = mk2(0.f, 0.f);
#pragma unroll
        for (int v = 0; v < T; ++v) {
            f2 d2 = mk2(0.f, 0.f);
#pragma unroll
            for (int m2 = 0; m2 < 4; ++m2) d2 = fma2(pri2[v][m2], on2[m2], d2);
            const float e = __expf(d2.x + d2.y);
            a8 += e;
            const f2 e2 = mk2(e, e);
#pragma unroll
            for (int m2 = 0; m2 < 4; ++m2) acc2[m2] = fma2(e2, pri2[v][m2], acc2[m2]);
        }
#pragma unroll
        for (int m2 = 0; m2 < 4; ++m2) {
            rr[m2].x = sum8(acc2[m2].x);
            rr[m2].y = sum8(acc2[m2].y);
        }
        if (it == NITER - 1) r8v = sum8(a8);  // denominator only needed once
    }
    const float invs = __builtin_amdgcn_rcpf(r8v + Z);  // zero votes: exp(0)=1
    const f2 invs2 = mk2(invs, invs);
    f2 o2[4];
#pragma unroll
    for (int m2 = 0; m2 < 4; ++m2) o2[m2] = rr[m2] * invs2;
    f2 s2 = mk2(0.f, 0.f);
#pragma unroll
    for (int m2 = 0; m2 < 4; ++m2) s2 = fma2(o2[m2], o2[m2], s2);
    const float sn = s2.x + s2.y;
    const float factor =
        sn * __builtin_amdgcn_rcpf(1.f + sn) * __builtin_amdgcn_rsqf(sn + 1e-12f);
    f2 osel = o2[0];
#pragma unroll
    for (int m2 = 1; m2 < 4; ++m2)
        if ((s >> 1) == m2) osel = o2[m2];
    float val = (s & 1) ? osel.y : osel.x;
    return val * factor + bias[g * 8 + s];
}

// ---- dual-position path (T<=2): one wave does q and q+8, sharing every
// weight ds_read between the two positions. Block covers 8 positions.
template <int TH, int TW>
__device__ __forceinline__ void run_dual(
    const float* __restrict__ in, const float* __restrict__ weight,
    const float* __restrict__ bias, float* __restrict__ out,
    float* __restrict__ ilds, float* __restrict__ wlds, float* __restrict__ olds,
    int t, int n, int p, int pi, int qb, int x0) {
    constexpr int T = TH * TW;
    stage_input<TH, (TW == 2 ? 3 : 2)>(in, ilds, t, n, pi, x0);
    stage_weights<TH, TW>(weight, wlds, t);
    __syncthreads();

    const int wave = t >> 6;
    const int lane = t & 63;
    const int g = lane >> 3;
    const int s = lane & 7;
    const int qa = qb + 2 * wave;

    f2 pa[T][4], pb[T][4];
    compute_pri<TH, TW>(ilds, wlds, qa, x0, pi, g, s, pa);
    compute_pri<TH, TW>(ilds, wlds, qa + 8, x0, pi, g, s, pb);

    const float va = route_core<T>(pa, bias, g, s);
    const float vb = route_core<T>(pb, bias, g, s);

    olds[lane * 9 + wave] = va;
    olds[lane * 9 + wave + 4] = vb;
    __syncthreads();
    const int c2 = t >> 2, w = t & 3;
    float* ob = out + (((size_t)n * 64 + c2) * 64 + p) * 64 + qb;
    ob[2 * w] = olds[c2 * 9 + w];
    ob[2 * w + 8] = olds[c2 * 9 + w + 4];
}

// ---- T=4 path: single position/wave (dual would spill: R5 lesson) ----
__device__ __forceinline__ void run_t4(
    const float* __restrict__ in, const float* __restrict__ weight,
    const float* __restrict__ bias, float* __restrict__ out,
    float* __restrict__ ilds, float* __restrict__ wlds, float* __restrict__ olds,
    int t, int n, int p, int pi, int qb, int x0) {
    stage_input<2, 2>(in, ilds, t, n, pi, x0);
    stage_weights<2, 2>(weight, wlds, t);
    __syncthreads();

    const int wave = t >> 6;
    const int lane = t & 63;
    const int g = lane >> 3;
    const int s = lane & 7;

    f2 pa[4][4];
    compute_pri<2, 2>(ilds, wlds, qb + 2 * wave, x0, pi, g, s, pa);
    const float va = route_core<4>(pa, bias, g, s);

    olds[lane * 5 + wave] = va;
    __syncthreads();
    const int c2 = t >> 2, w = t & 3;
    out[(((size_t)n * 64 + c2) * 64 + p) * 64 + qb + 2 * w] = olds[c2 * 5 + w];
}

// Grid 1280, quadrant-interleaved: blockIdx%5 -> {T4,T4,T2v,T2h,T1} so every
// CU gets a balanced mix (T4 blocks do ~3x the LDS work of T1).
__global__ __launch_bounds__(256) void caps_routing(
    const float* __restrict__ in, const float* __restrict__ weight,
    const float* __restrict__ bias, float* __restrict__ out) {
    __shared__ float ilds[2 * 12 * 64];  // input tile [yi][xi][c]
    __shared__ float wlds[4 * 640];      // staged taps (pk layout)
    __shared__ float olds[576];          // output staging
    const int t = threadIdx.x;

    const int b = blockIdx.x;
    const int grp = b / 5;        // 0..255
    const int sel = b - grp * 5;  // 0..4

    if (sel < 2) {  // T4: p odd, q odd; 512 blocks, 4 positions each
        const int idx = grp * 2 + sel;
        const int n = idx >> 8, r = idx & 255;
        const int pi = r >> 3, jq = r & 7;
        run_t4(in, weight, bias, out, ilds, wlds, olds,
               t, n, 2 * pi + 1, pi, 8 * jq + 1, 4 * jq);
    } else {  // dual paths: 256 blocks each, 8 positions each
        const int n = grp >> 7, r = grp & 127;
        const int pi = r >> 2, jq = r & 3;
        if (sel == 2)       // T2v: p odd, q even
            run_dual<2, 1>(in, weight, bias, out, ilds, wlds, olds,
                           t, n, 2 * pi + 1, pi, 16 * jq, 8 * jq);
        else if (sel == 3)  // T2h: p even, q odd
            run_dual<1, 2>(in, weight, bias, out, ilds, wlds, olds,
                           t, n, 2 * pi, pi, 16 * jq + 1, 8 * jq);
        else                // T1: p even, q even
            run_dual<1, 1>(in, weight, bias, out, ilds, wlds, olds,
                           t, n, 2 * pi, pi, 16 * jq, 8 * jq);
    }
}

extern "C" void kernel_launch(void* const* d_in, const int* in_sizes, int n_in,
                              void* d_out, int out_size, void* d_ws, size_t ws_size,
                              hipStream_t stream) {
    const float* in = (const float*)d_in[0];
    const float* weight = (const float*)d_in[1];
    const float* bias = (const float*)d_in[2];
    float* out = (float*)d_out;
    (void)d_ws; (void)ws_size;

    caps_routing<<<1280, 256, 0, stream>>>(in, weight, bias, out);
}